// Round 1
// baseline (248.992 us; speedup 1.0000x reference)
//
#include <hip/hip_runtime.h>

#define NQ   8192      // N queries per batch
#define NP   8192      // M points per batch
#define NF   128       // feature dim
#define NOUT 512       // output dim
#define NB   2         // batches
#define KNN  10
#define BNQ  (NB*NQ)   // 16384 total queries

typedef unsigned long long u64;

__device__ __forceinline__ u64 shfl64(u64 v, int src) {
  unsigned lo = (unsigned)__shfl((int)(unsigned)(v & 0xffffffffull), src, 64);
  unsigned hi = (unsigned)__shfl((int)(unsigned)(v >> 32), src, 64);
  return ((u64)hi << 32) | lo;
}
__device__ __forceinline__ u64 shflup64(u64 v) {
  unsigned lo = (unsigned)__shfl_up((int)(unsigned)(v & 0xffffffffull), 1, 64);
  unsigned hi = (unsigned)__shfl_up((int)(unsigned)(v >> 32), 1, 64);
  return ((u64)hi << 32) | lo;
}

// ---------------------------------------------------------------------------
// Prep: pack points as (x,y,z,|p|^2) and transpose W[512][128] -> Wt[128][512]
// ---------------------------------------------------------------------------
__global__ __launch_bounds__(256) void prep_kernel(
    const float* __restrict__ gpcd, const float* __restrict__ W,
    float4* __restrict__ pts4, float* __restrict__ Wt)
{
  int tid = blockIdx.x * 256 + threadIdx.x;   // 0..65535
  if (tid < NB * NP) {
    const float* p = gpcd + (size_t)tid * 3;
    float x = p[0], y = p[1], z = p[2];
    float p2 = x * x + y * y + z * z;
    pts4[tid] = make_float4(x, y, z, p2);
  }
  // W has 512*128 = 65536 elements; grid is exactly 65536 threads
  int o = tid >> 7, f = tid & 127;
  Wt[(size_t)f * NOUT + o] = W[tid];
}

// ---------------------------------------------------------------------------
// Stage A+B: per-wave kNN (4 queries/wave) + inverse-distance interp.
// Top-10 kept distributed across lanes 0..9 as sorted u64 keys (d2|idx).
// Writes interp transposed: At[f][q].
// ---------------------------------------------------------------------------
__global__ __launch_bounds__(256) void knn_interp_kernel(
    const float* __restrict__ geometry, const float4* __restrict__ pts4,
    const float* __restrict__ features, float* __restrict__ At)
{
  const int lane = threadIdx.x & 63;
  const int wave = (blockIdx.x << 2) | (threadIdx.x >> 6);
  const int q0   = wave << 2;           // 4 consecutive queries (same batch: 8192%4==0)
  const int b    = q0 >> 13;            // q0 / 8192
  const float4* __restrict__ P = pts4 + ((size_t)b << 13);

  float qx[4], qy[4], qz[4], q2[4];
#pragma unroll
  for (int j = 0; j < 4; ++j) {
    const float* g = geometry + (size_t)(q0 + j) * 3;
    qx[j] = g[0]; qy[j] = g[1]; qz[j] = g[2];
    q2[j] = qx[j] * qx[j] + qy[j] * qy[j] + qz[j] * qz[j];
  }

  u64 list[4]  = {~0ull, ~0ull, ~0ull, ~0ull};
  u64 theta[4] = {~0ull, ~0ull, ~0ull, ~0ull};

  for (int t = 0; t < NP / 64; ++t) {
    const int m = (t << 6) | lane;
    const float4 p = P[m];
#pragma unroll
    for (int j = 0; j < 4; ++j) {
      float dot = qx[j] * p.x + qy[j] * p.y + qz[j] * p.z;
      float d2  = (q2[j] + p.w) - 2.0f * dot;
      d2 = fmaxf(d2, 0.0f);                       // clamp BEFORE packing (sign bit!)
      u64 key = ((u64)__float_as_uint(d2) << 32) | (unsigned)m;
      u64 mask = __ballot(key < theta[j]);
      while (mask) {
        int src = __builtin_ctzll(mask); mask &= mask - 1;
        u64 kk   = shfl64(key, src);
        u64 prev = shflup64(list[j]);
        bool mylt = list[j] < kk;
        bool pins = (lane == 0) || (prev < kk);
        list[j] = mylt ? list[j] : (pins ? kk : prev);
        theta[j] = shfl64(list[j], 9);
      }
    }
  }

  // ---- weights + feature interpolation ----
  const float* __restrict__ F = features + (size_t)b * NP * NF;
#pragma unroll
  for (int j = 0; j < 4; ++j) {
    float d2s = __uint_as_float((unsigned)(list[j] >> 32));
    float w   = 1.0f / (sqrtf(d2s) + 1e-8f);      // meaningful on lanes 0..9
    float wsum = 0.0f;
#pragma unroll
    for (int jj = 0; jj < KNN; ++jj) wsum += __shfl(w, jj, 64);

    float a0 = 0.0f, a1 = 0.0f;
#pragma unroll
    for (int jj = 0; jj < KNN; ++jj) {
      float wj = __shfl(w, jj, 64) / wsum;
      int  mi  = (int)(unsigned)(shfl64(list[j], jj) & 0xffffffffull);
      const float2 f2 = *(const float2*)(F + (size_t)mi * NF + (lane << 1));
      a0 = fmaf(wj, f2.x, a0);
      a1 = fmaf(wj, f2.y, a1);
    }
    At[(size_t)(lane << 1) * BNQ + (q0 + j)]       = a0;
    At[(size_t)((lane << 1) + 1) * BNQ + (q0 + j)] = a1;
  }
}

// ---------------------------------------------------------------------------
// Stage C: out[q][o] = sum_f At[f][q] * Wt[f][o] + bias[o]
// 64x64 block tile, 4x4 per thread, LDS-free (tiles are L1/L2 resident).
// ---------------------------------------------------------------------------
__global__ __launch_bounds__(256) void proj_kernel(
    const float* __restrict__ At, const float* __restrict__ Wt,
    const float* __restrict__ bias, float* __restrict__ out)
{
  const int mt = blockIdx.x & 255;       // 256 m-tiles; consecutive blocks share Wt slice
  const int ot = blockIdx.x >> 8;        // 8 o-tiles
  const int tx = threadIdx.x & 15;
  const int ty = threadIdx.x >> 4;
  const int m0 = (mt << 6) + (ty << 2);
  const int o0 = (ot << 6) + (tx << 2);

  float acc[4][4];
#pragma unroll
  for (int i = 0; i < 4; ++i)
#pragma unroll
    for (int jj = 0; jj < 4; ++jj) acc[i][jj] = 0.0f;

#pragma unroll 8
  for (int k = 0; k < NF; ++k) {
    const float4 a  = *(const float4*)(At + (size_t)k * BNQ + m0);
    const float4 bv = *(const float4*)(Wt + (size_t)k * NOUT + o0);
    float av[4] = {a.x, a.y, a.z, a.w};
    float bw[4] = {bv.x, bv.y, bv.z, bv.w};
#pragma unroll
    for (int i = 0; i < 4; ++i)
#pragma unroll
      for (int jj = 0; jj < 4; ++jj)
        acc[i][jj] = fmaf(av[i], bw[jj], acc[i][jj]);
  }

  const float4 bb = *(const float4*)(bias + o0);
  float bias4[4] = {bb.x, bb.y, bb.z, bb.w};
#pragma unroll
  for (int i = 0; i < 4; ++i) {
    float4 r;
    r.x = acc[i][0] + bias4[0];
    r.y = acc[i][1] + bias4[1];
    r.z = acc[i][2] + bias4[2];
    r.w = acc[i][3] + bias4[3];
    *(float4*)(out + (size_t)(m0 + i) * NOUT + o0) = r;
  }
}

// ---------------------------------------------------------------------------
extern "C" void kernel_launch(void* const* d_in, const int* in_sizes, int n_in,
                              void* d_out, int out_size, void* d_ws, size_t ws_size,
                              hipStream_t stream) {
  const float* geometry = (const float*)d_in[0];   // [2,8192,3]
  const float* gpcd     = (const float*)d_in[1];   // [2,8192,3]
  const float* features = (const float*)d_in[2];   // [2,8192,128]
  const float* W        = (const float*)d_in[3];   // [512,128]
  const float* bias     = (const float*)d_in[4];   // [512]
  // d_in[5] = k (==10, hard-coded)
  float* out = (float*)d_out;

  // workspace layout (8.9 MB total)
  char*   ws   = (char*)d_ws;
  float*  At   = (float*)ws;                              // 128*16384 f32 = 8 MiB
  float4* pts4 = (float4*)(ws + (size_t)NF * BNQ * 4);    // 16384 * 16 B
  float*  Wt   = (float*)(ws + (size_t)NF * BNQ * 4 + (size_t)NB * NP * 16);

  prep_kernel<<<256, 256, 0, stream>>>(gpcd, W, pts4, Wt);
  knn_interp_kernel<<<BNQ / 16, 256, 0, stream>>>(geometry, pts4, features, At);
  proj_kernel<<<(BNQ / 64) * (NOUT / 64), 256, 0, stream>>>(At, Wt, bias, out);
}

// Round 3
// 207.911 us; speedup vs baseline: 1.1976x; 1.1976x over previous
//
#include <hip/hip_runtime.h>
#include <math.h>

#define NQ   8192      // N queries per batch
#define NP   8192      // M points per batch
#define NF   128       // feature dim
#define NOUT 512       // output dim
#define NB   2         // batches
#define KNN  10
#define BNQ  (NB*NQ)   // 16384 total queries
#define QW   2         // queries per wave

typedef unsigned long long u64;

__device__ __forceinline__ u64 shfl64(u64 v, int src) {
  unsigned lo = (unsigned)__shfl((int)(unsigned)(v & 0xffffffffull), src, 64);
  unsigned hi = (unsigned)__shfl((int)(unsigned)(v >> 32), src, 64);
  return ((u64)hi << 32) | lo;
}
__device__ __forceinline__ u64 shflup64(u64 v) {
  unsigned lo = (unsigned)__shfl_up((int)(unsigned)(v & 0xffffffffull), 1, 64);
  unsigned hi = (unsigned)__shfl_up((int)(unsigned)(v >> 32), 1, 64);
  return ((u64)hi << 32) | lo;
}

// ---------------------------------------------------------------------------
// Prep: pack points as (x,y,z,|p|^2) and transpose W[512][128] -> Wt[128][512]
// ---------------------------------------------------------------------------
__global__ __launch_bounds__(256) void prep_kernel(
    const float* __restrict__ gpcd, const float* __restrict__ W,
    float4* __restrict__ pts4, float* __restrict__ Wt)
{
  int tid = blockIdx.x * 256 + threadIdx.x;   // 0..65535
  if (tid < NB * NP) {
    const float* p = gpcd + (size_t)tid * 3;
    float x = p[0], y = p[1], z = p[2];
    float p2 = x * x + y * y + z * z;
    pts4[tid] = make_float4(x, y, z, p2);
  }
  int o = tid >> 7, f = tid & 127;
  Wt[(size_t)f * NOUT + o] = W[tid];
}

// ---------------------------------------------------------------------------
// Stage A+B: per-wave kNN (QW queries/wave) + inverse-distance interp.
// Top-10 distributed across lanes 0..9 as sorted u64 keys (d2|idx), float
// shadow dl[] for the d2 values. theta = 10th-best d2 via readlane (SGPR).
// Ballot uses STRICT d2 < theta: candidates are processed in ascending index
// order, so an equal-d2 candidate can never outrank the current 10th
// (lexicographic (d2,idx) order) — matches lax.top_k tie-breaks exactly.
// Processed lanes mark d2 = NaN (all compares false -> leaves every ballot).
// ---------------------------------------------------------------------------
__global__ __launch_bounds__(256) void knn_interp_kernel(
    const float* __restrict__ geometry, const float4* __restrict__ pts4,
    const float* __restrict__ features, float* __restrict__ At)
{
  const int lane = threadIdx.x & 63;
  const int wave = (blockIdx.x << 2) | (threadIdx.x >> 6);
  const int q0   = wave * QW;           // QW consecutive queries (same batch)
  const int b    = q0 >> 13;            // q0 / 8192
  const float4* __restrict__ P = pts4 + ((size_t)b << 13);

  float qx[QW], qy[QW], qz[QW], q2[QW];
#pragma unroll
  for (int j = 0; j < QW; ++j) {
    const float* g = geometry + (size_t)(q0 + j) * 3;
    qx[j] = g[0]; qy[j] = g[1]; qz[j] = g[2];
    q2[j] = qx[j] * qx[j] + qy[j] * qy[j] + qz[j] * qz[j];
  }

  u64   list[QW];
  float dl[QW], theta[QW];
#pragma unroll
  for (int j = 0; j < QW; ++j) {
    list[j]  = 0x7F800000FFFFFFFFull;   // (+inf d2, idx=~0)
    dl[j]    = INFINITY;
    theta[j] = INFINITY;
  }

  const float qnan = __builtin_nanf("");

  for (int t = 0; t < NP / 64; ++t) {
    const float4 p = P[(t << 6) | lane];
#pragma unroll
    for (int j = 0; j < QW; ++j) {
      float dot = qx[j] * p.x + qy[j] * p.y + qz[j] * p.z;
      float d2  = (q2[j] + p.w) - 2.0f * dot;
      d2 = fmaxf(d2, 0.0f);
      // pruned candidate loop: re-ballot against updated theta each iter
      for (;;) {
        u64 mask = __ballot(d2 < theta[j]);
        if (!mask) break;
        int src = __builtin_ctzll(mask);
        // candidate (d2, idx) — d2 via readlane (scalar), idx scalar
        float cd = __uint_as_float(
            (unsigned)__builtin_amdgcn_readlane(__float_as_int(d2), src));
        u64 kk = ((u64)__float_as_uint(cd) << 32) | (unsigned)((t << 6) + src);
        u64   prev  = shflup64(list[j]);
        float prevd = __shfl(dl[j], lane - 1, 64);  // shfl_up by 1
        bool mylt = list[j] < kk;
        bool pins = (lane == 0) || (prev < kk);
        list[j] = mylt ? list[j] : (pins ? kk : prev);
        dl[j]   = mylt ? dl[j]  : (pins ? cd : prevd);
        theta[j] = __uint_as_float(
            (unsigned)__builtin_amdgcn_readlane(__float_as_int(dl[j]), 9));
        if (lane == src) d2 = qnan;   // processed: exits all future ballots
      }
    }
  }

  // ---- weights + feature interpolation ----
  const float* __restrict__ F = features + (size_t)b * NP * NF;
#pragma unroll
  for (int j = 0; j < QW; ++j) {
    float w = 1.0f / (sqrtf(dl[j]) + 1e-8f);      // meaningful on lanes 0..9
    float wsum = 0.0f;
#pragma unroll
    for (int jj = 0; jj < KNN; ++jj) wsum += __shfl(w, jj, 64);

    float a0 = 0.0f, a1 = 0.0f;
#pragma unroll
    for (int jj = 0; jj < KNN; ++jj) {
      float wj = __shfl(w, jj, 64) / wsum;
      int  mi  = (int)(unsigned)(shfl64(list[j], jj) & 0xffffffffull);
      const float2 f2 = *(const float2*)(F + (size_t)mi * NF + (lane << 1));
      a0 = fmaf(wj, f2.x, a0);
      a1 = fmaf(wj, f2.y, a1);
    }
    At[(size_t)(lane << 1) * BNQ + (q0 + j)]       = a0;
    At[(size_t)((lane << 1) + 1) * BNQ + (q0 + j)] = a1;
  }
}

// ---------------------------------------------------------------------------
// Stage C: out[q][o] = sum_f At[f][q] * Wt[f][o] + bias[o]
// 64x64 block tile, 4x4 per thread, LDS-free (tiles are L1/L2 resident).
// ---------------------------------------------------------------------------
__global__ __launch_bounds__(256) void proj_kernel(
    const float* __restrict__ At, const float* __restrict__ Wt,
    const float* __restrict__ bias, float* __restrict__ out)
{
  const int mt = blockIdx.x & 255;
  const int ot = blockIdx.x >> 8;
  const int tx = threadIdx.x & 15;
  const int ty = threadIdx.x >> 4;
  const int m0 = (mt << 6) + (ty << 2);
  const int o0 = (ot << 6) + (tx << 2);

  float acc[4][4];
#pragma unroll
  for (int i = 0; i < 4; ++i)
#pragma unroll
    for (int jj = 0; jj < 4; ++jj) acc[i][jj] = 0.0f;

#pragma unroll 8
  for (int k = 0; k < NF; ++k) {
    const float4 a  = *(const float4*)(At + (size_t)k * BNQ + m0);
    const float4 bv = *(const float4*)(Wt + (size_t)k * NOUT + o0);
    float av[4] = {a.x, a.y, a.z, a.w};
    float bw[4] = {bv.x, bv.y, bv.z, bv.w};
#pragma unroll
    for (int i = 0; i < 4; ++i)
#pragma unroll
      for (int jj = 0; jj < 4; ++jj)
        acc[i][jj] = fmaf(av[i], bw[jj], acc[i][jj]);
  }

  const float4 bb = *(const float4*)(bias + o0);
  float bias4[4] = {bb.x, bb.y, bb.z, bb.w};
#pragma unroll
  for (int i = 0; i < 4; ++i) {
    float4 r;
    r.x = acc[i][0] + bias4[0];
    r.y = acc[i][1] + bias4[1];
    r.z = acc[i][2] + bias4[2];
    r.w = acc[i][3] + bias4[3];
    *(float4*)(out + (size_t)(m0 + i) * NOUT + o0) = r;
  }
}

// ---------------------------------------------------------------------------
extern "C" void kernel_launch(void* const* d_in, const int* in_sizes, int n_in,
                              void* d_out, int out_size, void* d_ws, size_t ws_size,
                              hipStream_t stream) {
  const float* geometry = (const float*)d_in[0];   // [2,8192,3]
  const float* gpcd     = (const float*)d_in[1];   // [2,8192,3]
  const float* features = (const float*)d_in[2];   // [2,8192,128]
  const float* W        = (const float*)d_in[3];   // [512,128]
  const float* bias     = (const float*)d_in[4];   // [512]
  float* out = (float*)d_out;

  char*   ws   = (char*)d_ws;
  float*  At   = (float*)ws;                              // 128*16384 f32 = 8 MiB
  float4* pts4 = (float4*)(ws + (size_t)NF * BNQ * 4);    // 16384 * 16 B
  float*  Wt   = (float*)(ws + (size_t)NF * BNQ * 4 + (size_t)NB * NP * 16);

  prep_kernel<<<256, 256, 0, stream>>>(gpcd, W, pts4, Wt);
  knn_interp_kernel<<<BNQ / (QW * 4), 256, 0, stream>>>(geometry, pts4, features, At);
  proj_kernel<<<(BNQ / 64) * (NOUT / 64), 256, 0, stream>>>(At, Wt, bias, out);
}

// Round 4
// 185.121 us; speedup vs baseline: 1.3450x; 1.1231x over previous
//
#include <hip/hip_runtime.h>
#include <math.h>

#define NQ   8192      // N queries per batch
#define NP   8192      // M points per batch
#define NF   128       // feature dim
#define NOUT 512       // output dim
#define NB   2         // batches
#define KNN  10
#define BNQ  (NB*NQ)   // 16384 total queries
#define QW   2         // queries per wave

typedef unsigned long long u64;

__device__ __forceinline__ u64 shfl64(u64 v, int src) {
  unsigned lo = (unsigned)__shfl((int)(unsigned)(v & 0xffffffffull), src, 64);
  unsigned hi = (unsigned)__shfl((int)(unsigned)(v >> 32), src, 64);
  return ((u64)hi << 32) | lo;
}
__device__ __forceinline__ u64 shflup64(u64 v) {
  unsigned lo = (unsigned)__shfl_up((int)(unsigned)(v & 0xffffffffull), 1, 64);
  unsigned hi = (unsigned)__shfl_up((int)(unsigned)(v >> 32), 1, 64);
  return ((u64)hi << 32) | lo;
}

// Deterministic distance: identical instruction sequence in pass 1 and pass 2
// (explicit fmaf; no compiler-contraction ambiguity at the tau boundary).
__device__ __forceinline__ float dist2(float qx, float qy, float qz, float q2c,
                                       float4 p) {
  float dot = fmaf(qx, p.x, fmaf(qy, p.y, qz * p.z));
  return fmaxf(fmaf(-2.0f, dot, q2c + p.w), 0.0f);
}

__device__ __forceinline__ float wmin64f(float v) {
#pragma unroll
  for (int off = 1; off < 64; off <<= 1)
    v = fminf(v, __shfl_xor(v, off, 64));
  return v;   // broadcast min across all 64 lanes
}

// ---------------------------------------------------------------------------
// Prep: pack points as (x,y,z,|p|^2) and transpose W[512][128] -> Wt[128][512]
// ---------------------------------------------------------------------------
__global__ __launch_bounds__(256) void prep_kernel(
    const float* __restrict__ gpcd, const float* __restrict__ W,
    float4* __restrict__ pts4, float* __restrict__ Wt)
{
  int tid = blockIdx.x * 256 + threadIdx.x;   // 0..65535
  if (tid < NB * NP) {
    const float* p = gpcd + (size_t)tid * 3;
    float x = p[0], y = p[1], z = p[2];
    float p2 = x * x + y * y + z * z;
    pts4[tid] = make_float4(x, y, z, p2);
  }
  int o = tid >> 7, f = tid & 127;
  Wt[(size_t)f * NOUT + o] = W[tid];
}

// ---------------------------------------------------------------------------
// Stage A+B: per-wave kNN (QW queries/wave) + inverse-distance interp.
// Pass 1: per-lane min d2 over its 128 points; tau = 10th-smallest lane-min
//   (knockout reduce). Guarantee: >=10 lanes have min <= tau => tau >= d_(10),
//   so seeding theta = tau+1ulp loses no true neighbor.
// Pass 2: round-3 verified distributed insert (lanes 0..9 hold sorted top-10
//   as u64 (d2|idx) keys), but candidates pre-filtered by theta ~ tau:
//   ~12-15 inserts/query instead of ~100 (no cold-start flood).
// ---------------------------------------------------------------------------
__global__ __launch_bounds__(256) void knn_interp_kernel(
    const float* __restrict__ geometry, const float4* __restrict__ pts4,
    const float* __restrict__ features, float* __restrict__ At)
{
  const int lane = threadIdx.x & 63;
  const int wave = (blockIdx.x << 2) | (threadIdx.x >> 6);
  const int q0   = wave * QW;           // QW consecutive queries (same batch)
  const int b    = q0 >> 13;            // q0 / 8192
  const float4* __restrict__ P = pts4 + ((size_t)b << 13);

  float qx[QW], qy[QW], qz[QW], q2[QW];
#pragma unroll
  for (int j = 0; j < QW; ++j) {
    const float* g = geometry + (size_t)(q0 + j) * 3;
    qx[j] = g[0]; qy[j] = g[1]; qz[j] = g[2];
    q2[j] = qx[j] * qx[j] + qy[j] * qy[j] + qz[j] * qz[j];
  }

  // ---- pass 1: per-lane min ----
  float lmin[QW];
#pragma unroll
  for (int j = 0; j < QW; ++j) lmin[j] = INFINITY;
  for (int t = 0; t < NP / 64; ++t) {
    const float4 p = P[(t << 6) | lane];
#pragma unroll
    for (int j = 0; j < QW; ++j)
      lmin[j] = fminf(lmin[j], dist2(qx[j], qy[j], qz[j], q2[j], p));
  }

  // ---- tau = 10th-smallest lane-min (with multiplicity); theta = tau+1ulp --
  float theta[QW];
#pragma unroll
  for (int j = 0; j < QW; ++j) {
    float lm  = lmin[j];
    float tau = 0.0f;
#pragma unroll
    for (int r = 0; r < KNN; ++r) {
      tau = wmin64f(lm);
      u64 mk = __ballot(lm == tau);
      int w  = __builtin_ctzll(mk);
      if (lane == w) lm = INFINITY;     // knock out one holder per round
    }
    theta[j] = __uint_as_float(__float_as_uint(tau) + 1);  // include d2 == tau
  }

  u64   list[QW];
  float dl[QW];
#pragma unroll
  for (int j = 0; j < QW; ++j) {
    list[j] = 0x7F800000FFFFFFFFull;    // (+inf d2, idx=~0)
    dl[j]   = INFINITY;
  }
  const float qnan = __builtin_nanf("");

  // ---- pass 2: exact filtered insert ----
  for (int t = 0; t < NP / 64; ++t) {
    const float4 p = P[(t << 6) | lane];
#pragma unroll
    for (int j = 0; j < QW; ++j) {
      float d2 = dist2(qx[j], qy[j], qz[j], q2[j], p);
      for (;;) {
        u64 mask = __ballot(d2 < theta[j]);
        if (!mask) break;
        int src = __builtin_ctzll(mask);
        float cd = __uint_as_float(
            (unsigned)__builtin_amdgcn_readlane(__float_as_int(d2), src));
        u64 kk = ((u64)__float_as_uint(cd) << 32) | (unsigned)((t << 6) + src);
        u64   prev  = shflup64(list[j]);
        float prevd = __shfl(dl[j], lane - 1, 64);  // shfl_up by 1
        bool mylt = list[j] < kk;
        bool pins = (lane == 0) || (prev < kk);
        list[j] = mylt ? list[j] : (pins ? kk : prev);
        dl[j]   = mylt ? dl[j]  : (pins ? cd : prevd);
        // min(): while list is underfull dl[9]=INF must not lift theta
        theta[j] = fminf(theta[j], __uint_as_float(
            (unsigned)__builtin_amdgcn_readlane(__float_as_int(dl[j]), 9)));
        if (lane == src) d2 = qnan;     // processed: exits all future ballots
      }
    }
  }

  // ---- weights + feature interpolation ----
  const float* __restrict__ F = features + (size_t)b * NP * NF;
#pragma unroll
  for (int j = 0; j < QW; ++j) {
    float w = 1.0f / (sqrtf(dl[j]) + 1e-8f);      // meaningful on lanes 0..9
    float wsum = 0.0f;
#pragma unroll
    for (int jj = 0; jj < KNN; ++jj) wsum += __shfl(w, jj, 64);

    float a0 = 0.0f, a1 = 0.0f;
#pragma unroll
    for (int jj = 0; jj < KNN; ++jj) {
      float wj = __shfl(w, jj, 64) / wsum;
      int  mi  = (int)(unsigned)(shfl64(list[j], jj) & 0xffffffffull);
      const float2 f2 = *(const float2*)(F + (size_t)mi * NF + (lane << 1));
      a0 = fmaf(wj, f2.x, a0);
      a1 = fmaf(wj, f2.y, a1);
    }
    At[(size_t)(lane << 1) * BNQ + (q0 + j)]       = a0;
    At[(size_t)((lane << 1) + 1) * BNQ + (q0 + j)] = a1;
  }
}

// ---------------------------------------------------------------------------
// Stage C: out[q][o] = sum_f At[f][q] * Wt[f][o] + bias[o]
// 64x64 block tile, 4x4 per thread, LDS-free (tiles are L1/L2 resident).
// ---------------------------------------------------------------------------
__global__ __launch_bounds__(256) void proj_kernel(
    const float* __restrict__ At, const float* __restrict__ Wt,
    const float* __restrict__ bias, float* __restrict__ out)
{
  const int mt = blockIdx.x & 255;
  const int ot = blockIdx.x >> 8;
  const int tx = threadIdx.x & 15;
  const int ty = threadIdx.x >> 4;
  const int m0 = (mt << 6) + (ty << 2);
  const int o0 = (ot << 6) + (tx << 2);

  float acc[4][4];
#pragma unroll
  for (int i = 0; i < 4; ++i)
#pragma unroll
    for (int jj = 0; jj < 4; ++jj) acc[i][jj] = 0.0f;

#pragma unroll 8
  for (int k = 0; k < NF; ++k) {
    const float4 a  = *(const float4*)(At + (size_t)k * BNQ + m0);
    const float4 bv = *(const float4*)(Wt + (size_t)k * NOUT + o0);
    float av[4] = {a.x, a.y, a.z, a.w};
    float bw[4] = {bv.x, bv.y, bv.z, bv.w};
#pragma unroll
    for (int i = 0; i < 4; ++i)
#pragma unroll
      for (int jj = 0; jj < 4; ++jj)
        acc[i][jj] = fmaf(av[i], bw[jj], acc[i][jj]);
  }

  const float4 bb = *(const float4*)(bias + o0);
  float bias4[4] = {bb.x, bb.y, bb.z, bb.w};
#pragma unroll
  for (int i = 0; i < 4; ++i) {
    float4 r;
    r.x = acc[i][0] + bias4[0];
    r.y = acc[i][1] + bias4[1];
    r.z = acc[i][2] + bias4[2];
    r.w = acc[i][3] + bias4[3];
    *(float4*)(out + (size_t)(m0 + i) * NOUT + o0) = r;
  }
}

// ---------------------------------------------------------------------------
extern "C" void kernel_launch(void* const* d_in, const int* in_sizes, int n_in,
                              void* d_out, int out_size, void* d_ws, size_t ws_size,
                              hipStream_t stream) {
  const float* geometry = (const float*)d_in[0];   // [2,8192,3]
  const float* gpcd     = (const float*)d_in[1];   // [2,8192,3]
  const float* features = (const float*)d_in[2];   // [2,8192,128]
  const float* W        = (const float*)d_in[3];   // [512,128]
  const float* bias     = (const float*)d_in[4];   // [512]
  float* out = (float*)d_out;

  char*   ws   = (char*)d_ws;
  float*  At   = (float*)ws;                              // 128*16384 f32 = 8 MiB
  float4* pts4 = (float4*)(ws + (size_t)NF * BNQ * 4);    // 16384 * 16 B
  float*  Wt   = (float*)(ws + (size_t)NF * BNQ * 4 + (size_t)NB * NP * 16);

  prep_kernel<<<256, 256, 0, stream>>>(gpcd, W, pts4, Wt);
  knn_interp_kernel<<<BNQ / (QW * 4), 256, 0, stream>>>(geometry, pts4, features, At);
  proj_kernel<<<(BNQ / 64) * (NOUT / 64), 256, 0, stream>>>(At, Wt, bias, out);
}

// Round 5
// 130.339 us; speedup vs baseline: 1.9103x; 1.4203x over previous
//
#include <hip/hip_runtime.h>
#include <math.h>

#define NQ   8192      // N queries per batch
#define NP   8192      // M points per batch
#define NF   128       // feature dim
#define NOUT 512       // output dim
#define NB   2         // batches
#define KNN  10
#define BNQ  (NB*NQ)   // 16384 total queries
#define QW   4         // queries per wave

typedef unsigned long long u64;

__device__ __forceinline__ u64 shfl64(u64 v, int src) {
  unsigned lo = (unsigned)__shfl((int)(unsigned)(v & 0xffffffffull), src, 64);
  unsigned hi = (unsigned)__shfl((int)(unsigned)(v >> 32), src, 64);
  return ((u64)hi << 32) | lo;
}
__device__ __forceinline__ u64 shflup64(u64 v) {
  unsigned lo = (unsigned)__shfl_up((int)(unsigned)(v & 0xffffffffull), 1, 64);
  unsigned hi = (unsigned)__shfl_up((int)(unsigned)(v >> 32), 1, 64);
  return ((u64)hi << 32) | lo;
}

// Deterministic distance, identical sequence in both passes. NO clamp here:
// pass 1 clamps the accumulated min once; pass 2 clamps candidates only.
// d2 = ((q2+p2) + (-2qz)*pz) + (-2qy)*py + (-2qx)*px   (3 fma + 1 add)
__device__ __forceinline__ float dist2m(float m2x, float m2y, float m2z,
                                        float q2c, float4 p) {
  return fmaf(m2x, p.x, fmaf(m2y, p.y, fmaf(m2z, p.z, q2c + p.w)));
}

__device__ __forceinline__ float wmin64f(float v) {
#pragma unroll
  for (int off = 1; off < 64; off <<= 1)
    v = fminf(v, __shfl_xor(v, off, 64));
  return v;   // broadcast min across all 64 lanes
}

// ---------------------------------------------------------------------------
// Prep: pack points as (x,y,z,|p|^2) and transpose W[512][128] -> Wt[128][512]
// ---------------------------------------------------------------------------
__global__ __launch_bounds__(256) void prep_kernel(
    const float* __restrict__ gpcd, const float* __restrict__ W,
    float4* __restrict__ pts4, float* __restrict__ Wt)
{
  int tid = blockIdx.x * 256 + threadIdx.x;   // 0..65535
  if (tid < NB * NP) {
    const float* p = gpcd + (size_t)tid * 3;
    float x = p[0], y = p[1], z = p[2];
    float p2 = x * x + y * y + z * z;
    pts4[tid] = make_float4(x, y, z, p2);
  }
  int o = tid >> 7, f = tid & 127;
  Wt[(size_t)f * NOUT + o] = W[tid];
}

// ---------------------------------------------------------------------------
// Stage A+B: per-wave kNN (QW queries/wave) + inverse-distance interp.
// Pass 1: per-lane min d2 over its 128 points; tau = 10th-smallest lane-min.
// Pass 2: tau-filtered distributed insert (lanes 0..9 hold sorted top-10).
// ---------------------------------------------------------------------------
__global__ __launch_bounds__(256) void knn_interp_kernel(
    const float* __restrict__ geometry, const float4* __restrict__ pts4,
    const float* __restrict__ features, float* __restrict__ At)
{
  const int lane = threadIdx.x & 63;
  const int wave = (blockIdx.x << 2) | (threadIdx.x >> 6);
  const int q0   = wave * QW;           // QW consecutive queries (same batch)
  const int b    = q0 >> 13;            // q0 / 8192
  const float4* __restrict__ P = pts4 + ((size_t)b << 13);

  float m2x[QW], m2y[QW], m2z[QW], q2[QW];
#pragma unroll
  for (int j = 0; j < QW; ++j) {
    const float* g = geometry + (size_t)(q0 + j) * 3;
    float x = g[0], y = g[1], z = g[2];
    q2[j]  = x * x + y * y + z * z;
    m2x[j] = -2.0f * x; m2y[j] = -2.0f * y; m2z[j] = -2.0f * z;
  }

  // ---- pass 1: per-lane min (unclamped) ----
  float lmin[QW];
#pragma unroll
  for (int j = 0; j < QW; ++j) lmin[j] = INFINITY;
#pragma unroll 2
  for (int t = 0; t < NP / 64; ++t) {
    const float4 p = P[(t << 6) | lane];
#pragma unroll
    for (int j = 0; j < QW; ++j)
      lmin[j] = fminf(lmin[j], dist2m(m2x[j], m2y[j], m2z[j], q2[j], p));
  }
#pragma unroll
  for (int j = 0; j < QW; ++j) lmin[j] = fmaxf(lmin[j], 0.0f);  // clamp once

  // ---- tau = 10th-smallest lane-min (with multiplicity); theta = tau+1ulp --
  float theta[QW];
#pragma unroll
  for (int j = 0; j < QW; ++j) {
    float lm  = lmin[j];
    float tau = 0.0f;
#pragma unroll
    for (int r = 0; r < KNN; ++r) {
      tau = wmin64f(lm);
      u64 mk = __ballot(lm == tau);
      int w  = __builtin_ctzll(mk);
      if (lane == w) lm = INFINITY;     // knock out one holder per round
    }
    theta[j] = __uint_as_float(__float_as_uint(tau) + 1);  // include d2 == tau
  }

  u64   list[QW];
  float dl[QW];
#pragma unroll
  for (int j = 0; j < QW; ++j) {
    list[j] = 0x7F800000FFFFFFFFull;    // (+inf d2, idx=~0)
    dl[j]   = INFINITY;
  }
  const float qnan = __builtin_nanf("");

  // ---- pass 2: exact filtered insert ----
  for (int t = 0; t < NP / 64; ++t) {
    const float4 p = P[(t << 6) | lane];
#pragma unroll
    for (int j = 0; j < QW; ++j) {
      float d2 = dist2m(m2x[j], m2y[j], m2z[j], q2[j], p);
      // unclamped d2 vs theta(>=0): negative d2 still ballots true (correct)
      for (;;) {
        u64 mask = __ballot(d2 < theta[j]);
        if (!mask) break;
        int src = __builtin_ctzll(mask);
        float cd = __uint_as_float(
            (unsigned)__builtin_amdgcn_readlane(__float_as_int(d2), src));
        cd = fmaxf(cd, 0.0f);           // clamp candidate (matches reference)
        u64 kk = ((u64)__float_as_uint(cd) << 32) | (unsigned)((t << 6) + src);
        u64   prev  = shflup64(list[j]);
        float prevd = __shfl(dl[j], lane - 1, 64);  // shfl_up by 1
        bool mylt = list[j] < kk;
        bool pins = (lane == 0) || (prev < kk);
        list[j] = mylt ? list[j] : (pins ? kk : prev);
        dl[j]   = mylt ? dl[j]  : (pins ? cd : prevd);
        // min(): while list is underfull dl[9]=INF must not lift theta
        theta[j] = fminf(theta[j], __uint_as_float(
            (unsigned)__builtin_amdgcn_readlane(__float_as_int(dl[j]), 9)));
        if (lane == src) d2 = qnan;     // processed: exits all future ballots
      }
    }
  }

  // ---- weights + feature interpolation ----
  const float* __restrict__ F = features + (size_t)b * NP * NF;
#pragma unroll
  for (int j = 0; j < QW; ++j) {
    float w = 1.0f / (sqrtf(dl[j]) + 1e-8f);      // meaningful on lanes 0..9
    float wsum = 0.0f;
#pragma unroll
    for (int jj = 0; jj < KNN; ++jj) wsum += __shfl(w, jj, 64);

    float a0 = 0.0f, a1 = 0.0f;
#pragma unroll
    for (int jj = 0; jj < KNN; ++jj) {
      float wj = __shfl(w, jj, 64) / wsum;
      int  mi  = (int)(unsigned)(shfl64(list[j], jj) & 0xffffffffull);
      const float2 f2 = *(const float2*)(F + (size_t)mi * NF + (lane << 1));
      a0 = fmaf(wj, f2.x, a0);
      a1 = fmaf(wj, f2.y, a1);
    }
    At[(size_t)(lane << 1) * BNQ + (q0 + j)]       = a0;
    At[(size_t)((lane << 1) + 1) * BNQ + (q0 + j)] = a1;
  }
}

// ---------------------------------------------------------------------------
// Stage C: out[q][o] = sum_f At[f][q] * Wt[f][o] + bias[o]
// LDS-tiled: 64x64 block tile, KC=64 two-chunk, 4x4 per thread.
// Pad rows to 68 floats (272 B, 16B-aligned) to spread LDS banks.
// LDS = 2*64*68*4 = 34 KB -> 4 blocks/CU.
// ---------------------------------------------------------------------------
#define PKC  64
#define PLD  68

__global__ __launch_bounds__(256) void proj_kernel(
    const float* __restrict__ At, const float* __restrict__ Wt,
    const float* __restrict__ bias, float* __restrict__ out)
{
  __shared__ __align__(16) float lds_a[PKC][PLD];
  __shared__ __align__(16) float lds_b[PKC][PLD];

  const int mt = blockIdx.x & 255;       // 256 m-tiles
  const int ot = blockIdx.x >> 8;        // 8 o-tiles
  const int tx = threadIdx.x & 15;
  const int ty = threadIdx.x >> 4;
  const int m0 = mt << 6;
  const int o0 = ot << 6;

  const int lr = threadIdx.x >> 4;          // loader row 0..15
  const int lc = (threadIdx.x & 15) << 2;   // loader col quad

  float acc[4][4];
#pragma unroll
  for (int i = 0; i < 4; ++i)
#pragma unroll
    for (int jj = 0; jj < 4; ++jj) acc[i][jj] = 0.0f;

#pragma unroll
  for (int kc = 0; kc < NF / PKC; ++kc) {
    const int k0 = kc * PKC;
#pragma unroll
    for (int rp = 0; rp < 4; ++rp) {
      const int r = (rp << 4) + lr;
      const float4 a4 = *(const float4*)(At + (size_t)(k0 + r) * BNQ  + m0 + lc);
      const float4 b4 = *(const float4*)(Wt + (size_t)(k0 + r) * NOUT + o0 + lc);
      *(float4*)(&lds_a[r][lc]) = a4;
      *(float4*)(&lds_b[r][lc]) = b4;
    }
    __syncthreads();
#pragma unroll 8
    for (int k = 0; k < PKC; ++k) {
      const float4 a  = *(const float4*)(&lds_a[k][ty << 2]);
      const float4 bv = *(const float4*)(&lds_b[k][tx << 2]);
      float av[4] = {a.x, a.y, a.z, a.w};
      float bw[4] = {bv.x, bv.y, bv.z, bv.w};
#pragma unroll
      for (int i = 0; i < 4; ++i)
#pragma unroll
        for (int jj = 0; jj < 4; ++jj)
          acc[i][jj] = fmaf(av[i], bw[jj], acc[i][jj]);
    }
    __syncthreads();
  }

  const float4 bb = *(const float4*)(bias + o0 + (tx << 2));
  float bias4[4] = {bb.x, bb.y, bb.z, bb.w};
#pragma unroll
  for (int i = 0; i < 4; ++i) {
    float4 r;
    r.x = acc[i][0] + bias4[0];
    r.y = acc[i][1] + bias4[1];
    r.z = acc[i][2] + bias4[2];
    r.w = acc[i][3] + bias4[3];
    *(float4*)(out + (size_t)(m0 + (ty << 2) + i) * NOUT + o0 + (tx << 2)) = r;
  }
}

// ---------------------------------------------------------------------------
extern "C" void kernel_launch(void* const* d_in, const int* in_sizes, int n_in,
                              void* d_out, int out_size, void* d_ws, size_t ws_size,
                              hipStream_t stream) {
  const float* geometry = (const float*)d_in[0];   // [2,8192,3]
  const float* gpcd     = (const float*)d_in[1];   // [2,8192,3]
  const float* features = (const float*)d_in[2];   // [2,8192,128]
  const float* W        = (const float*)d_in[3];   // [512,128]
  const float* bias     = (const float*)d_in[4];   // [512]
  float* out = (float*)d_out;

  char*   ws   = (char*)d_ws;
  float*  At   = (float*)ws;                              // 128*16384 f32 = 8 MiB
  float4* pts4 = (float4*)(ws + (size_t)NF * BNQ * 4);    // 16384 * 16 B
  float*  Wt   = (float*)(ws + (size_t)NF * BNQ * 4 + (size_t)NB * NP * 16);

  prep_kernel<<<256, 256, 0, stream>>>(gpcd, W, pts4, Wt);
  knn_interp_kernel<<<BNQ / (QW * 4), 256, 0, stream>>>(geometry, pts4, features, At);
  proj_kernel<<<(BNQ / 64) * (NOUT / 64), 256, 0, stream>>>(At, Wt, bias, out);
}